// Round 1
// 378.267 us; speedup vs baseline: 1.0200x; 1.0200x over previous
//
#include <hip/hip_runtime.h>

// Matcher: B=8, H=W=48, HW=2304.  Row-linear single-pass design, zero atomics.
// out[b,0..1,:]: global branch  max_p init_sim[b,p,j]*init_seg[b,c,p]
// out[b,2..3,:]: local branch   per-row top4/min on scaled prev_sim rows,
//                column max of (kept value | per-row fill).
//
// Structure: one wave holds a full 2304-float row in 36 VGPRs (9 KB linear
// read), computes top4+min in-register (insert chain + shfl_xor butterfly),
// then both channels' contributions from the same registers, accumulating
// per-column max in 72 VGPRs.  prev_sim is read ONCE (old design read it
// twice and used 3KB/9KB-stride column chunks).
#define B_   8
#define HW_  2304
#define NP   64              // row-chunks (blocks per batch): 512 blocks = 2/CU
#define RP   36              // rows per block
#define RW   9               // rows per wave (4 waves/block, interleaved)
#define NOUT (B_ * 4 * HW_)

// ws layout (float units)
#define PG_OFF 0                       // global partials: B*2*NP*HW floats (9.44 MB)
#define PL_OFF (B_ * 2 * NP * HW_)     // local  partials: B*2*NP*HW floats

// ---------------------------------------------------------------------------
// Local branch: one kernel, row-linear. Each wave: load row -> top4/min
// (in-reg + butterfly) -> per-element contribution -> column-max registers.
__global__ __launch_bounds__(256, 2) void k_local(const float* __restrict__ sim,
                                                  const float* __restrict__ seg,
                                                  float* __restrict__ P) {
    const int np   = blockIdx.x;            // 0..NP-1
    const int b    = blockIdx.y;
    const int wid  = threadIdx.x >> 6;
    const int lane = threadIdx.x & 63;
    const float* simb = sim + (size_t)b * HW_ * HW_;
    const float* sg   = seg + (size_t)b * 2 * HW_;
    const int p0 = np * RP;
    const float NI = -__builtin_inff();

    float m0[36], m1[36];
#pragma unroll
    for (int k = 0; k < 36; ++k) { m0[k] = NI; m1[k] = NI; }

#pragma unroll 1
    for (int rr = 0; rr < RW; ++rr) {
        const int p = p0 + rr * 4 + wid;                 // wave-uniform row id
        const float4* row = (const float4*)(simb + (size_t)p * HW_);
        float x[36];
#pragma unroll
        for (int k = 0; k < 9; ++k) {
            float4 v = row[lane + (k << 6)];
            x[4 * k + 0] = v.x; x[4 * k + 1] = v.y;
            x[4 * k + 2] = v.z; x[4 * k + 3] = v.w;
        }
        // per-lane top4 (sorted desc) + min over this lane's 36 raw values
        float a0 = NI, a1 = NI, a2 = NI, a3 = NI, mn = __builtin_inff();
#pragma unroll
        for (int k = 0; k < 36; ++k) {
            float v = x[k];
            mn = fminf(mn, v);
            float w = fmaxf(a3, v);                      // branchless insert
            a3 = fminf(a2, w); w = fmaxf(a2, w);
            a2 = fminf(a1, w); w = fmaxf(a1, w);
            a1 = fminf(a0, w); a0 = fmaxf(a0, w);
        }
        // xor-butterfly merge of sorted 4-lists: result lands in ALL lanes
#pragma unroll
        for (int off = 1; off <= 32; off <<= 1) {
            float b0 = __shfl_xor(a0, off);
            float b1 = __shfl_xor(a1, off);
            float b2 = __shfl_xor(a2, off);
            float b3 = __shfl_xor(a3, off);
            float bm = __shfl_xor(mn, off);
            mn = fminf(mn, bm);
            float r0 = fmaxf(a0, b0);
            float r1 = fmaxf(fmaxf(a1, b1), fminf(a0, b0));
            float r2 = fmaxf(fmaxf(a2, b2), fmaxf(fminf(a1, b0), fminf(a0, b1)));
            float r3 = fmaxf(fmaxf(a3, b3),
                       fmaxf(fminf(a2, b0), fmaxf(fminf(a1, b1), fminf(a0, b2))));
            a0 = r0; a1 = r1; a2 = r2; a3 = r3;
        }
        // row scalars (wave-uniform); seg >= 0 so scaled top4/min = s * raw
        const int pu = __builtin_amdgcn_readfirstlane(p);
        const float s0 = sg[pu], s1 = sg[HW_ + pu];
        const float cut0 = s0 * a3, mnv0 = s0 * mn, fill0 = fmaxf(mnv0, 0.f);
        const float cut1 = s1 * a3, mnv1 = s1 * mn, fill1 = fmaxf(mnv1, 0.f);
#pragma unroll
        for (int k = 0; k < 36; ++k) {
            float v0 = x[k] * s0, v1 = x[k] * s1;
            float e0 = fmaxf(v0 - mnv0, 0.f) + mnv0;     // == ref bitwise
            float e1 = fmaxf(v1 - mnv1, 0.f) + mnv1;
            float c0 = (v0 >= cut0) ? e0 : fill0;
            float c1 = (v1 >= cut1) ? e1 : fill1;
            m0[k] = fmaxf(m0[k], c0);
            m1[k] = fmaxf(m1[k], c1);
        }
    }

    // combine the 4 waves' column-max in LDS (serialized RMW), then store
    __shared__ float4 lm[2][HW_ / 4];
    if (wid == 0) {
#pragma unroll
        for (int k = 0; k < 9; ++k) {
            lm[0][lane + (k << 6)] = make_float4(m0[4*k], m0[4*k+1], m0[4*k+2], m0[4*k+3]);
            lm[1][lane + (k << 6)] = make_float4(m1[4*k], m1[4*k+1], m1[4*k+2], m1[4*k+3]);
        }
    }
    __syncthreads();
#pragma unroll
    for (int w = 1; w < 4; ++w) {
        if (wid == w) {
#pragma unroll
            for (int k = 0; k < 9; ++k) {
                float4 c = lm[0][lane + (k << 6)];
                c.x = fmaxf(c.x, m0[4*k+0]); c.y = fmaxf(c.y, m0[4*k+1]);
                c.z = fmaxf(c.z, m0[4*k+2]); c.w = fmaxf(c.w, m0[4*k+3]);
                lm[0][lane + (k << 6)] = c;
                float4 d = lm[1][lane + (k << 6)];
                d.x = fmaxf(d.x, m1[4*k+0]); d.y = fmaxf(d.y, m1[4*k+1]);
                d.z = fmaxf(d.z, m1[4*k+2]); d.w = fmaxf(d.w, m1[4*k+3]);
                lm[1][lane + (k << 6)] = d;
            }
        }
        __syncthreads();
    }
    float4* P4 = (float4*)P;
    const size_t pb0 = (((size_t)b * 2 + 0) * NP + np) * (HW_ / 4);
    const size_t pb1 = (((size_t)b * 2 + 1) * NP + np) * (HW_ / 4);
    for (int i = threadIdx.x; i < HW_ / 4; i += 256) {
        P4[pb0 + i] = lm[0][i];
        P4[pb1 + i] = lm[1][i];
    }
}

// ---------------------------------------------------------------------------
// Global branch: same row-linear skeleton, no top4 needed.
__global__ __launch_bounds__(256, 2) void k_glob(const float* __restrict__ sim,
                                                 const float* __restrict__ seg,
                                                 float* __restrict__ P) {
    const int np   = blockIdx.x;
    const int b    = blockIdx.y;
    const int wid  = threadIdx.x >> 6;
    const int lane = threadIdx.x & 63;
    const float* simb = sim + (size_t)b * HW_ * HW_;
    const float* sg   = seg + (size_t)b * 2 * HW_;
    const int p0 = np * RP;
    const float NI = -__builtin_inff();

    float4 M0[9], M1[9];
#pragma unroll
    for (int k = 0; k < 9; ++k) { M0[k] = make_float4(NI, NI, NI, NI); M1[k] = M0[k]; }

#pragma unroll 1
    for (int rr = 0; rr < RW; ++rr) {
        const int p = p0 + rr * 4 + wid;
        const float4* row = (const float4*)(simb + (size_t)p * HW_);
        const int pu = __builtin_amdgcn_readfirstlane(p);
        const float s0 = sg[pu], s1 = sg[HW_ + pu];
#pragma unroll
        for (int k = 0; k < 9; ++k) {
            float4 v = row[lane + (k << 6)];
            M0[k].x = fmaxf(M0[k].x, v.x * s0); M1[k].x = fmaxf(M1[k].x, v.x * s1);
            M0[k].y = fmaxf(M0[k].y, v.y * s0); M1[k].y = fmaxf(M1[k].y, v.y * s1);
            M0[k].z = fmaxf(M0[k].z, v.z * s0); M1[k].z = fmaxf(M1[k].z, v.z * s1);
            M0[k].w = fmaxf(M0[k].w, v.w * s0); M1[k].w = fmaxf(M1[k].w, v.w * s1);
        }
    }

    __shared__ float4 lm[2][HW_ / 4];
    if (wid == 0) {
#pragma unroll
        for (int k = 0; k < 9; ++k) {
            lm[0][lane + (k << 6)] = M0[k];
            lm[1][lane + (k << 6)] = M1[k];
        }
    }
    __syncthreads();
#pragma unroll
    for (int w = 1; w < 4; ++w) {
        if (wid == w) {
#pragma unroll
            for (int k = 0; k < 9; ++k) {
                float4 c = lm[0][lane + (k << 6)];
                c.x = fmaxf(c.x, M0[k].x); c.y = fmaxf(c.y, M0[k].y);
                c.z = fmaxf(c.z, M0[k].z); c.w = fmaxf(c.w, M0[k].w);
                lm[0][lane + (k << 6)] = c;
                float4 d = lm[1][lane + (k << 6)];
                d.x = fmaxf(d.x, M1[k].x); d.y = fmaxf(d.y, M1[k].y);
                d.z = fmaxf(d.z, M1[k].z); d.w = fmaxf(d.w, M1[k].w);
                lm[1][lane + (k << 6)] = d;
            }
        }
        __syncthreads();
    }
    float4* P4 = (float4*)P;
    const size_t pb0 = (((size_t)b * 2 + 0) * NP + np) * (HW_ / 4);
    const size_t pb1 = (((size_t)b * 2 + 1) * NP + np) * (HW_ / 4);
    for (int i = threadIdx.x; i < HW_ / 4; i += 256) {
        P4[pb0 + i] = lm[0][i];
        P4[pb1 + i] = lm[1][i];
    }
}

// ---------------------------------------------------------------------------
// Final: 64-way partial-max combine for all four channels.
__global__ __launch_bounds__(256) void k_final(float* __restrict__ out,
                                               const float* __restrict__ Pg,
                                               const float* __restrict__ Pl) {
    int idx = blockIdx.x * 256 + threadIdx.x;
    if (idx >= NOUT) return;
    int b = idx / (4 * HW_);
    int c = (idx / HW_) & 3;
    int j = idx % HW_;
    const float* p = ((c < 2) ? Pg : Pl) + (((size_t)b * 2 + (c & 1)) * NP) * HW_ + j;
    float m = -__builtin_inff();
#pragma unroll 8
    for (int np = 0; np < NP; ++np) m = fmaxf(m, p[(size_t)np * HW_]);
    out[idx] = m;
}

extern "C" void kernel_launch(void* const* d_in, const int* in_sizes, int n_in,
                              void* d_out, int out_size, void* d_ws, size_t ws_size,
                              hipStream_t stream) {
    const float* init_sim = (const float*)d_in[0];
    const float* prev_sim = (const float*)d_in[1];
    const float* init_seg = (const float*)d_in[2];
    const float* prev_seg = (const float*)d_in[3];
    float* ws = (float*)d_ws;
    float* Pg = ws + PG_OFF;
    float* Pl = ws + PL_OFF;

    k_glob <<<dim3(NP, B_), 256, 0, stream>>>(init_sim, init_seg, Pg);
    k_local<<<dim3(NP, B_), 256, 0, stream>>>(prev_sim, prev_seg, Pl);
    k_final<<<NOUT / 256, 256, 0, stream>>>((float*)d_out, Pg, Pl);
}

// Round 4
// 341.245 us; speedup vs baseline: 1.1307x; 1.1085x over previous
//
#include <hip/hip_runtime.h>

// Matcher: B=8, H=W=48, HW=2304.  Row-linear single-pass, zero atomics.
// out[b,0..1,:]: global branch  max_p init_sim[b,p,j]*init_seg[b,c,p]
// out[b,2..3,:]: local branch   per-row top4/min on scaled prev_sim rows,
//                column max of (kept value | per-row fill).
//
// Round-4: resubmit of round-3 (infra failure, never measured).
// Fused gridDim.z launch + nontemporal sim stream (native ext_vector type).
// All arithmetic bit-identical to the absmax=0 round-1 kernel.
#define B_   8
#define HW_  2304
#define NP   64              // row-chunks per batch
#define RP   36              // rows per block
#define RW   9               // rows per wave (4 waves/block, interleaved)
#define NOUT (B_ * 4 * HW_)

typedef float native_f4 __attribute__((ext_vector_type(4)));

// ws layout (float units)
#define PG_OFF 0                       // global partials: B*2*NP*HW floats (9.44 MB)
#define PL_OFF (B_ * 2 * NP * HW_)     // local  partials: B*2*NP*HW floats

// 4-wave LDS max-combine + partial store (shared by both branches).
__device__ __forceinline__ void combine_store(float* __restrict__ P, int b, int np,
                                              int wid, int lane,
                                              const float4* M0, const float4* M1,
                                              float4 (*lm)[HW_ / 4]) {
    if (wid == 0) {
#pragma unroll
        for (int k = 0; k < 9; ++k) {
            lm[0][lane + (k << 6)] = M0[k];
            lm[1][lane + (k << 6)] = M1[k];
        }
    }
    __syncthreads();
#pragma unroll
    for (int w = 1; w < 4; ++w) {
        if (wid == w) {
#pragma unroll
            for (int k = 0; k < 9; ++k) {
                float4 c = lm[0][lane + (k << 6)];
                c.x = fmaxf(c.x, M0[k].x); c.y = fmaxf(c.y, M0[k].y);
                c.z = fmaxf(c.z, M0[k].z); c.w = fmaxf(c.w, M0[k].w);
                lm[0][lane + (k << 6)] = c;
                float4 d = lm[1][lane + (k << 6)];
                d.x = fmaxf(d.x, M1[k].x); d.y = fmaxf(d.y, M1[k].y);
                d.z = fmaxf(d.z, M1[k].z); d.w = fmaxf(d.w, M1[k].w);
                lm[1][lane + (k << 6)] = d;
            }
        }
        __syncthreads();
    }
    float4* P4 = (float4*)P;
    const size_t pb0 = (((size_t)b * 2 + 0) * NP + np) * (HW_ / 4);
    const size_t pb1 = (((size_t)b * 2 + 1) * NP + np) * (HW_ / 4);
    const int t = wid * 64 + lane;
    for (int i = t; i < HW_ / 4; i += 256) {
        P4[pb0 + i] = lm[0][i];
        P4[pb1 + i] = lm[1][i];
    }
}

// Fused main kernel: z==0 -> global branch (init_*), z==1 -> local (prev_*).
__global__ __launch_bounds__(256, 2) void k_main(const float* __restrict__ init_sim,
                                                 const float* __restrict__ init_seg,
                                                 const float* __restrict__ prev_sim,
                                                 const float* __restrict__ prev_seg,
                                                 float* __restrict__ ws) {
    const int np   = blockIdx.x;
    const int b    = blockIdx.y;
    const int wid  = threadIdx.x >> 6;
    const int lane = threadIdx.x & 63;
    const int p0   = np * RP;
    const float NI = -__builtin_inff();
    __shared__ float4 lm[2][HW_ / 4];

    if (blockIdx.z == 0) {
        // ---------------- global branch: plain scaled column-max ----------
        const float* simb = init_sim + (size_t)b * HW_ * HW_;
        const float* sg   = init_seg + (size_t)b * 2 * HW_;
        float4 M0[9], M1[9];
#pragma unroll
        for (int k = 0; k < 9; ++k) { M0[k] = make_float4(NI, NI, NI, NI); M1[k] = M0[k]; }
#pragma unroll 1
        for (int rr = 0; rr < RW; ++rr) {
            const int p = p0 + rr * 4 + wid;                 // wave-uniform row
            const native_f4* row = (const native_f4*)(simb + (size_t)p * HW_);
            const int pu = __builtin_amdgcn_readfirstlane(p);
            const float s0 = sg[pu], s1 = sg[HW_ + pu];
#pragma unroll
            for (int k = 0; k < 9; ++k) {
                native_f4 v = __builtin_nontemporal_load(row + lane + (k << 6));
                M0[k].x = fmaxf(M0[k].x, v.x * s0); M1[k].x = fmaxf(M1[k].x, v.x * s1);
                M0[k].y = fmaxf(M0[k].y, v.y * s0); M1[k].y = fmaxf(M1[k].y, v.y * s1);
                M0[k].z = fmaxf(M0[k].z, v.z * s0); M1[k].z = fmaxf(M1[k].z, v.z * s1);
                M0[k].w = fmaxf(M0[k].w, v.w * s0); M1[k].w = fmaxf(M1[k].w, v.w * s1);
            }
        }
        combine_store(ws + PG_OFF, b, np, wid, lane, M0, M1, lm);
    } else {
        // ---------------- local branch: top4/min + contribution -----------
        const float* simb = prev_sim + (size_t)b * HW_ * HW_;
        const float* sg   = prev_seg + (size_t)b * 2 * HW_;
        float m0[36], m1[36];
#pragma unroll
        for (int k = 0; k < 36; ++k) { m0[k] = NI; m1[k] = NI; }
#pragma unroll 1
        for (int rr = 0; rr < RW; ++rr) {
            const int p = p0 + rr * 4 + wid;                 // wave-uniform row
            const native_f4* row = (const native_f4*)(simb + (size_t)p * HW_);
            float x[36];
#pragma unroll
            for (int k = 0; k < 9; ++k) {
                native_f4 v = __builtin_nontemporal_load(row + lane + (k << 6));
                x[4 * k + 0] = v.x; x[4 * k + 1] = v.y;
                x[4 * k + 2] = v.z; x[4 * k + 3] = v.w;
            }
            // per-lane top4 (sorted desc) + min over this lane's 36 values
            float a0 = NI, a1 = NI, a2 = NI, a3 = NI, mn = __builtin_inff();
#pragma unroll
            for (int k = 0; k < 36; ++k) {
                float v = x[k];
                mn = fminf(mn, v);
                float w = fmaxf(a3, v);                      // branchless insert
                a3 = fminf(a2, w); w = fmaxf(a2, w);
                a2 = fminf(a1, w); w = fmaxf(a1, w);
                a1 = fminf(a0, w); a0 = fmaxf(a0, w);
            }
            // xor-butterfly merge of sorted 4-lists: result in ALL lanes
#pragma unroll
            for (int off = 1; off <= 32; off <<= 1) {
                float b0 = __shfl_xor(a0, off);
                float b1 = __shfl_xor(a1, off);
                float b2 = __shfl_xor(a2, off);
                float b3 = __shfl_xor(a3, off);
                float bm = __shfl_xor(mn, off);
                mn = fminf(mn, bm);
                float r0 = fmaxf(a0, b0);
                float r1 = fmaxf(fmaxf(a1, b1), fminf(a0, b0));
                float r2 = fmaxf(fmaxf(a2, b2), fmaxf(fminf(a1, b0), fminf(a0, b1)));
                float r3 = fmaxf(fmaxf(a3, b3),
                           fmaxf(fminf(a2, b0), fmaxf(fminf(a1, b1), fminf(a0, b2))));
                a0 = r0; a1 = r1; a2 = r2; a3 = r3;
            }
            // row scalars (wave-uniform); seg >= 0 so scaled top4/min = s*raw
            const int pu = __builtin_amdgcn_readfirstlane(p);
            const float s0 = sg[pu], s1 = sg[HW_ + pu];
            const float cut0 = s0 * a3, mnv0 = s0 * mn, fill0 = fmaxf(mnv0, 0.f);
            const float cut1 = s1 * a3, mnv1 = s1 * mn, fill1 = fmaxf(mnv1, 0.f);
#pragma unroll
            for (int k = 0; k < 36; ++k) {
                float v0 = x[k] * s0, v1 = x[k] * s1;
                float e0 = fmaxf(v0 - mnv0, 0.f) + mnv0;     // == ref bitwise
                float e1 = fmaxf(v1 - mnv1, 0.f) + mnv1;
                float c0 = (v0 >= cut0) ? e0 : fill0;
                float c1 = (v1 >= cut1) ? e1 : fill1;
                m0[k] = fmaxf(m0[k], c0);
                m1[k] = fmaxf(m1[k], c1);
            }
        }
        float4 M0[9], M1[9];
#pragma unroll
        for (int k = 0; k < 9; ++k) {
            M0[k] = make_float4(m0[4*k], m0[4*k+1], m0[4*k+2], m0[4*k+3]);
            M1[k] = make_float4(m1[4*k], m1[4*k+1], m1[4*k+2], m1[4*k+3]);
        }
        combine_store(ws + PL_OFF, b, np, wid, lane, M0, M1, lm);
    }
}

// Final: 64-way partial-max combine for all four channels.
__global__ __launch_bounds__(256) void k_final(float* __restrict__ out,
                                               const float* __restrict__ Pg,
                                               const float* __restrict__ Pl) {
    int idx = blockIdx.x * 256 + threadIdx.x;
    if (idx >= NOUT) return;
    int b = idx / (4 * HW_);
    int c = (idx / HW_) & 3;
    int j = idx % HW_;
    const float* p = ((c < 2) ? Pg : Pl) + (((size_t)b * 2 + (c & 1)) * NP) * HW_ + j;
    float m = -__builtin_inff();
#pragma unroll 8
    for (int np = 0; np < NP; ++np) m = fmaxf(m, p[(size_t)np * HW_]);
    out[idx] = m;
}

extern "C" void kernel_launch(void* const* d_in, const int* in_sizes, int n_in,
                              void* d_out, int out_size, void* d_ws, size_t ws_size,
                              hipStream_t stream) {
    const float* init_sim = (const float*)d_in[0];
    const float* prev_sim = (const float*)d_in[1];
    const float* init_seg = (const float*)d_in[2];
    const float* prev_seg = (const float*)d_in[3];
    float* ws = (float*)d_ws;

    k_main <<<dim3(NP, B_, 2), 256, 0, stream>>>(init_sim, init_seg,
                                                 prev_sim, prev_seg, ws);
    k_final<<<NOUT / 256, 256, 0, stream>>>((float*)d_out,
                                            ws + PG_OFF, ws + PL_OFF);
}